// Round 25
// baseline (57.622 us; speedup 1.0000x reference)
//
#include <hip/hip_runtime.h>
#include <math.h>
#include <stdint.h>

#define NCLS 128
#define NBLK 256
constexpr float ALPHA = 0.5f;
constexpr float BETA_ = 0.5f;
constexpr float EPS_ = 1e-9f;

// ws: gLb[128][256] double (262144 B) | gceb[256] double (2048 B) | gcntb[128][256] uint (131072 B)
// No zero_ws kernel: every slot is plain-STORED by its owning block every launch
// (flush is atomic-free), so no pre-zeroing and one fewer dispatch in the graph.

// R22 champion streaming core (batch-8, sched_barrier load pin, owner-lane tv
// fold, wave-parallel epilogue, 256x1024 grid) + write-based flush.
__global__ __launch_bounds__(1024, 4) void loss_main(
    const float* __restrict__ y_pred,
    const int*   __restrict__ y_true,
    double* __restrict__ gLb, unsigned int* __restrict__ gcntb,
    double* __restrict__ gceb, int nrows)
{
    __shared__ float    sL[NCLS];
    __shared__ unsigned scnt[NCLS];
    __shared__ float    sce;

    const int t = threadIdx.x;
    if (t == 0) sce = 0.f;
    if (t < NCLS) { sL[t] = 0.f; scnt[t] = 0u; }
    __syncthreads();

    const int lane = t & 63;
    const int half = lane >> 5;
    const int l32  = lane & 31;
    const int wgl  = blockIdx.x * (blockDim.x >> 6) + (t >> 6);   // 0..4095
    const int nW   = gridDim.x * (blockDim.x >> 6);               // 4096
    const int nPairs = nrows >> 1;

    float ce_local = 0.f;

    int p0 = wgl * 8;
    for (; p0 + 7 < nPairs; p0 += nW * 8) {
        // ---- LOAD phase: 8x float4 (1KB/wave each) + 8 labels, all issued first
        float4 v[8]; int lab[8];
        const float* base = y_pred + ((size_t)(p0 << 1) + half) * NCLS + (l32 << 2);
        #pragma unroll
        for (int u = 0; u < 8; ++u) {
            v[u]   = *reinterpret_cast<const float4*>(base + (size_t)(u << 1) * NCLS);
            lab[u] = y_true[((p0 + u) << 1) + half];
        }
        __builtin_amdgcn_sched_barrier(0);   // pin: no compute issued before loads

        // ---- EXP phase: v dies here (S, e0, owner-lane tv fold)
        float S[8], e0[8];
        #pragma unroll
        for (int u = 0; u < 8; ++u) {
            const float ex = __expf(v[u].x), ey = __expf(v[u].y);
            const float ez = __expf(v[u].z), ew = __expf(v[u].w);
            e0[u] = ex;                      // valid on lane 0/32 (col 0) only
            S[u]  = (ex + ey) + (ez + ew);
            if ((lab[u] >> 2) == l32) {      // owner lane folds target logit now
                const int ls = lab[u] & 3;
                ce_local += (ls == 0) ? v[u].x : (ls == 1) ? v[u].y
                          : (ls == 2) ? v[u].z : v[u].w;
            }
        }
        // ---- 8 interleaved 5-step butterflies (S lands on all lanes)
        #pragma unroll
        for (int off = 16; off; off >>= 1) {
            #pragma unroll
            for (int u = 0; u < 8; ++u) S[u] += __shfl_xor(S[u], off);
        }
        // ---- distribute: lane l32==u owns row-pair u of its half
        float e0m = 1.f, Sm = 1.f; int labm = 0;
        #pragma unroll
        for (int u = 0; u < 8; ++u) {
            const float b = __shfl(e0[u], half << 5);   // bcast col-0 exp from lane 0/32
            if (l32 == u) { e0m = b; Sm = S[u]; labm = lab[u]; }
        }
        // ---- wave-parallel epilogue: 16 lanes (8 per half) at once
        if (l32 < 8) {
            const float logS = __logf(Sm);
            ce_local -= logS;
            const float d = (labm == 0) ? e0m : (Sm - e0m);
            const float c0 = __logf(__fmaf_rn(EPS_, Sm, d)) - logS;
            const float contrib = (labm == 0) ? ALPHA * c0 : c0;
            atomicAdd(&sL[labm], contrib);
            atomicAdd(&scnt[labm], 1u);
        }
    }
    // tail: leftover single pairs (empty at 262144 rows; kept for generality)
    for (; p0 < nPairs; ++p0) {
        const int row = (p0 << 1) + half;
        const float4 v = *reinterpret_cast<const float4*>(
            y_pred + (size_t)row * NCLS + (l32 << 2));
        const int lab = y_true[row];
        const float ex = __expf(v.x), ey = __expf(v.y);
        const float ez = __expf(v.z), ew = __expf(v.w);
        float S = (ex + ey) + (ez + ew);
        if ((lab >> 2) == l32) {
            const int ls = lab & 3;
            ce_local += (ls == 0) ? v.x : (ls == 1) ? v.y : (ls == 2) ? v.z : v.w;
        }
        #pragma unroll
        for (int off = 16; off; off >>= 1) S += __shfl_xor(S, off);
        if (l32 == 0) {
            const float logS = __logf(S);
            ce_local -= logS;
            const float d = (lab == 0) ? ex : (S - ex);
            const float c0 = __logf(__fmaf_rn(EPS_, S, d)) - logS;
            const float contrib = (lab == 0) ? ALPHA * c0 : c0;
            atomicAdd(&sL[lab], contrib);
            atomicAdd(&scnt[lab], 1u);
        }
    }
    if ((nrows & 1) && wgl == 0) {
        const int row = nrows - 1;
        const float4 v = *reinterpret_cast<const float4*>(
            y_pred + (size_t)row * NCLS + (l32 << 2));
        const int lab = y_true[row];
        if (half == 0) {
            const float ex = __expf(v.x), ey = __expf(v.y);
            const float ez = __expf(v.z), ew = __expf(v.w);
            float S = (ex + ey) + (ez + ew);
            if ((lab >> 2) == l32) {
                const int ls = lab & 3;
                ce_local += (ls == 0) ? v.x : (ls == 1) ? v.y : (ls == 2) ? v.z : v.w;
            }
            #pragma unroll
            for (int off = 16; off; off >>= 1) S += __shfl_xor(S, off);
            if (l32 == 0) {
                const float logS = __logf(S);
                ce_local -= logS;
                const float d = (lab == 0) ? ex : (S - ex);
                const float c0 = __logf(__fmaf_rn(EPS_, S, d)) - logS;
                const float contrib = (lab == 0) ? ALPHA * c0 : c0;
                atomicAdd(&sL[lab], contrib);
                atomicAdd(&scnt[lab], 1u);
            }
        }
    }

    float lp = ce_local;
    #pragma unroll
    for (int off = 32; off; off >>= 1) lp += __shfl_xor(lp, off);
    if (lane == 0) atomicAdd(&sce, lp);
    __syncthreads();

    // write-flush: each block OWNS slot blockIdx.x of every class row.
    // Plain stores (no atomics); every slot written every launch -> no zeroing.
    if (t < NCLS) {
        gLb[t * NBLK + blockIdx.x]   = (double)sL[t];
        gcntb[t * NBLK + blockIdx.x] = scnt[t];
    }
    if (t == 0) gceb[blockIdx.x] = (double)sce;
}

__global__ void loss_final(const double* __restrict__ gLb,
                           const unsigned int* __restrict__ gcntb,
                           const double* __restrict__ gceb,
                           float* __restrict__ out, int nrows)
{
    const int lane = threadIdx.x;   // 64 threads

    // class-0 count: lane-parallel partial + butterfly (needed by all lanes)
    double cnt0 = 0.0;
    for (int b = lane; b < NBLK; b += 64) cnt0 += (double)gcntb[b];
    #pragma unroll
    for (int off = 32; off; off >>= 1) cnt0 += __shfl_xor(cnt0, off);
    const double denom = (double)nrows - cnt0;

    double local = 0.0;
    for (int c = lane; c < NCLS; c += 64) {      // 2 classes per lane
        double Lc = 0.0, nc = 0.0;
        for (int b = 0; b < NBLK; ++b) {
            Lc += gLb[c * NBLK + b];
            nc += (double)gcntb[c * NBLK + b];
        }
        local += (c == 0) ? Lc                    // ALPHA pre-applied
               : (double)BETA_ * (1.0 - nc / denom) * Lc;
    }
    double cep = 0.0;
    for (int b = lane; b < NBLK; b += 64) cep += gceb[b];

    #pragma unroll
    for (int off = 32; off; off >>= 1) {
        local += __shfl_down(local, off);
        cep   += __shfl_down(cep, off);
    }
    if (lane == 0) {
        const double ce = -cep / (double)nrows;
        out[0] = (float)(ce - local / (double)nrows);
    }
}

extern "C" void kernel_launch(void* const* d_in, const int* in_sizes, int n_in,
                              void* d_out, int out_size, void* d_ws, size_t ws_size,
                              hipStream_t stream) {
    const float* y_pred = (const float*)d_in[0];
    const int*   y_true = (const int*)d_in[1];
    const int nrows = in_sizes[1];

    double*   gLb   = (double*)d_ws;                          // 262144 B
    double*   gceb  = (double*)((char*)d_ws + 262144);        // 2048 B
    unsigned* gcntb = (unsigned*)((char*)d_ws + 264192);      // 131072 B

    loss_main<<<dim3(NBLK), dim3(1024), 0, stream>>>(y_pred, y_true, gLb, gcntb, gceb, nrows);
    loss_final<<<dim3(1), dim3(64), 0, stream>>>(gLb, gcntb, gceb, (float*)d_out, nrows);
}

// Round 26
// 38.016 us; speedup vs baseline: 1.5157x; 1.5157x over previous
//
#include <hip/hip_runtime.h>
#include <math.h>
#include <stdint.h>

#define NCLS 128
#define NBLK 256
constexpr float ALPHA = 0.5f;
constexpr float BETA_ = 0.5f;
constexpr float EPS_ = 1e-9f;

// ws: gLb[256][128] double (262144 B) | gceb[256] double (2048 B) | gcntb[256][128] uint (131072 B)
// Atomic-free flush, TRANSPOSED layout [blk][cls]: each block's 128 stores are one
// coalesced 1KB burst. Every slot written every launch -> no zeroing, no zero_ws.

// R22 champion streaming core (batch-8, sched_barrier load pin, owner-lane tv
// fold, wave-parallel epilogue, 256x1024 grid) + coalesced write-flush.
__global__ __launch_bounds__(1024, 4) void loss_main(
    const float* __restrict__ y_pred,
    const int*   __restrict__ y_true,
    double* __restrict__ gLb, unsigned int* __restrict__ gcntb,
    double* __restrict__ gceb, int nrows)
{
    __shared__ float    sL[NCLS];
    __shared__ unsigned scnt[NCLS];
    __shared__ float    sce;

    const int t = threadIdx.x;
    if (t == 0) sce = 0.f;
    if (t < NCLS) { sL[t] = 0.f; scnt[t] = 0u; }
    __syncthreads();

    const int lane = t & 63;
    const int half = lane >> 5;
    const int l32  = lane & 31;
    const int wgl  = blockIdx.x * (blockDim.x >> 6) + (t >> 6);   // 0..4095
    const int nW   = gridDim.x * (blockDim.x >> 6);               // 4096
    const int nPairs = nrows >> 1;

    float ce_local = 0.f;

    int p0 = wgl * 8;
    for (; p0 + 7 < nPairs; p0 += nW * 8) {
        // ---- LOAD phase: 8x float4 (1KB/wave each) + 8 labels, all issued first
        float4 v[8]; int lab[8];
        const float* base = y_pred + ((size_t)(p0 << 1) + half) * NCLS + (l32 << 2);
        #pragma unroll
        for (int u = 0; u < 8; ++u) {
            v[u]   = *reinterpret_cast<const float4*>(base + (size_t)(u << 1) * NCLS);
            lab[u] = y_true[((p0 + u) << 1) + half];
        }
        __builtin_amdgcn_sched_barrier(0);   // pin: no compute issued before loads

        // ---- EXP phase: v dies here (S, e0, owner-lane tv fold)
        float S[8], e0[8];
        #pragma unroll
        for (int u = 0; u < 8; ++u) {
            const float ex = __expf(v[u].x), ey = __expf(v[u].y);
            const float ez = __expf(v[u].z), ew = __expf(v[u].w);
            e0[u] = ex;                      // valid on lane 0/32 (col 0) only
            S[u]  = (ex + ey) + (ez + ew);
            if ((lab[u] >> 2) == l32) {      // owner lane folds target logit now
                const int ls = lab[u] & 3;
                ce_local += (ls == 0) ? v[u].x : (ls == 1) ? v[u].y
                          : (ls == 2) ? v[u].z : v[u].w;
            }
        }
        // ---- 8 interleaved 5-step butterflies (S lands on all lanes)
        #pragma unroll
        for (int off = 16; off; off >>= 1) {
            #pragma unroll
            for (int u = 0; u < 8; ++u) S[u] += __shfl_xor(S[u], off);
        }
        // ---- distribute: lane l32==u owns row-pair u of its half
        float e0m = 1.f, Sm = 1.f; int labm = 0;
        #pragma unroll
        for (int u = 0; u < 8; ++u) {
            const float b = __shfl(e0[u], half << 5);   // bcast col-0 exp from lane 0/32
            if (l32 == u) { e0m = b; Sm = S[u]; labm = lab[u]; }
        }
        // ---- wave-parallel epilogue: 16 lanes (8 per half) at once
        if (l32 < 8) {
            const float logS = __logf(Sm);
            ce_local -= logS;
            const float d = (labm == 0) ? e0m : (Sm - e0m);
            const float c0 = __logf(__fmaf_rn(EPS_, Sm, d)) - logS;
            const float contrib = (labm == 0) ? ALPHA * c0 : c0;
            atomicAdd(&sL[labm], contrib);
            atomicAdd(&scnt[labm], 1u);
        }
    }
    // tail: leftover single pairs (empty at 262144 rows; kept for generality)
    for (; p0 < nPairs; ++p0) {
        const int row = (p0 << 1) + half;
        const float4 v = *reinterpret_cast<const float4*>(
            y_pred + (size_t)row * NCLS + (l32 << 2));
        const int lab = y_true[row];
        const float ex = __expf(v.x), ey = __expf(v.y);
        const float ez = __expf(v.z), ew = __expf(v.w);
        float S = (ex + ey) + (ez + ew);
        if ((lab >> 2) == l32) {
            const int ls = lab & 3;
            ce_local += (ls == 0) ? v.x : (ls == 1) ? v.y : (ls == 2) ? v.z : v.w;
        }
        #pragma unroll
        for (int off = 16; off; off >>= 1) S += __shfl_xor(S, off);
        if (l32 == 0) {
            const float logS = __logf(S);
            ce_local -= logS;
            const float d = (lab == 0) ? ex : (S - ex);
            const float c0 = __logf(__fmaf_rn(EPS_, S, d)) - logS;
            const float contrib = (lab == 0) ? ALPHA * c0 : c0;
            atomicAdd(&sL[lab], contrib);
            atomicAdd(&scnt[lab], 1u);
        }
    }
    if ((nrows & 1) && wgl == 0) {
        const int row = nrows - 1;
        const float4 v = *reinterpret_cast<const float4*>(
            y_pred + (size_t)row * NCLS + (l32 << 2));
        const int lab = y_true[row];
        if (half == 0) {
            const float ex = __expf(v.x), ey = __expf(v.y);
            const float ez = __expf(v.z), ew = __expf(v.w);
            float S = (ex + ey) + (ez + ew);
            if ((lab >> 2) == l32) {
                const int ls = lab & 3;
                ce_local += (ls == 0) ? v.x : (ls == 1) ? v.y : (ls == 2) ? v.z : v.w;
            }
            #pragma unroll
            for (int off = 16; off; off >>= 1) S += __shfl_xor(S, off);
            if (l32 == 0) {
                const float logS = __logf(S);
                ce_local -= logS;
                const float d = (lab == 0) ? ex : (S - ex);
                const float c0 = __logf(__fmaf_rn(EPS_, S, d)) - logS;
                const float contrib = (lab == 0) ? ALPHA * c0 : c0;
                atomicAdd(&sL[lab], contrib);
                atomicAdd(&scnt[lab], 1u);
            }
        }
    }

    float lp = ce_local;
    #pragma unroll
    for (int off = 32; off; off >>= 1) lp += __shfl_xor(lp, off);
    if (lane == 0) atomicAdd(&sce, lp);
    __syncthreads();

    // coalesced write-flush: block owns row blockIdx.x of [blk][cls] arrays.
    if (t < NCLS) {
        gLb[(size_t)blockIdx.x * NCLS + t]   = (double)sL[t];
        gcntb[(size_t)blockIdx.x * NCLS + t] = scnt[t];
    }
    if (t == 0) gceb[blockIdx.x] = (double)sce;
}

// Parallel finalize: 1024 threads. 8 threads per class x 32 slots, coalesced
// (for fixed slot b, lanes read consecutive classes). LDS tree + wave butterflies.
__global__ __launch_bounds__(1024) void loss_final(
    const double* __restrict__ gLb,          // [256][128]
    const unsigned int* __restrict__ gcntb,  // [256][128]
    const double* __restrict__ gceb,         // [256]
    float* __restrict__ out, int nrows)
{
    __shared__ double sLc[8][NCLS];
    __shared__ double snc[8][NCLS];
    __shared__ double sred[4];

    const int t = threadIdx.x;
    const int c = t & (NCLS - 1);
    const int g = t >> 7;                    // 0..7

    double Lc = 0.0, nc = 0.0;
    for (int b = g * 32; b < g * 32 + 32; ++b) {
        Lc += gLb[(size_t)b * NCLS + c];
        nc += (double)gcntb[(size_t)b * NCLS + c];
    }
    sLc[g][c] = Lc; snc[g][c] = nc;
    __syncthreads();

    if (t < NCLS) {
        double L = 0.0, n = 0.0;
        #pragma unroll
        for (int gg = 0; gg < 8; ++gg) { L += sLc[gg][t]; n += snc[gg][t]; }
        sLc[0][t] = L; snc[0][t] = n;
    }
    __syncthreads();

    const double denom = (double)nrows - snc[0][0];
    double local = 0.0;
    if (t < NCLS) {
        const double L = sLc[0][t], n = snc[0][t];
        local = (t == 0) ? L : (double)BETA_ * (1.0 - n / denom) * L;
    }
    #pragma unroll
    for (int off = 32; off; off >>= 1) local += __shfl_xor(local, off);
    if (t < NCLS && (t & 63) == 0) sred[t >> 6] = local;   // sred[0], sred[1]

    if (t >= 128 && t < 192) {               // one wave sums gceb[256]
        const int l = t - 128;
        double cep = gceb[l] + gceb[l + 64] + gceb[l + 128] + gceb[l + 192];
        #pragma unroll
        for (int off = 32; off; off >>= 1) cep += __shfl_xor(cep, off);
        if (l == 0) sred[2] = cep;
    }
    __syncthreads();

    if (t == 0) {
        const double ce = -sred[2] / (double)nrows;
        out[0] = (float)(ce - (sred[0] + sred[1]) / (double)nrows);
    }
}

extern "C" void kernel_launch(void* const* d_in, const int* in_sizes, int n_in,
                              void* d_out, int out_size, void* d_ws, size_t ws_size,
                              hipStream_t stream) {
    const float* y_pred = (const float*)d_in[0];
    const int*   y_true = (const int*)d_in[1];
    const int nrows = in_sizes[1];

    double*   gLb   = (double*)d_ws;                          // 262144 B
    double*   gceb  = (double*)((char*)d_ws + 262144);        // 2048 B
    unsigned* gcntb = (unsigned*)((char*)d_ws + 264192);      // 131072 B

    loss_main<<<dim3(NBLK), dim3(1024), 0, stream>>>(y_pred, y_true, gLb, gcntb, gceb, nrows);
    loss_final<<<dim3(1), dim3(1024), 0, stream>>>(gLb, gcntb, gceb, (float*)d_out, nrows);
}